// Round 3
// baseline (387.279 us; speedup 1.0000x reference)
//
#include <hip/hip_runtime.h>

// LatentLinearModel: out[i] = dot(U[users[i]], V[jokes[i]]) + a[users[i]] + b[jokes[i]] + g
// K=64 floats/row = 256 B contiguous.
//
// R2 analysis: kernel ~130us vs ~55us gather floor; wave lifetime was a
// serial 3-miss chain (idx -> rows -> biases). R3: persistent grid-stride
// with software pipeline: next iter's indices prefetched during current
// gathers; bias loads hoisted next to row gathers; U/V interleaved so
// stepwise vmcnt waits leave later gathers in flight.

constexpr int KV  = 16;   // float4s per 64-float row
constexpr int RPG = 4;    // rows per 16-lane group per iteration

__global__ __launch_bounds__(256) void latent_linear_kernel(
    const int* __restrict__ users,
    const int* __restrict__ jokes,
    const float* __restrict__ U,
    const float* __restrict__ V,
    const float* __restrict__ a,
    const float* __restrict__ b,
    const float* __restrict__ g,
    float* __restrict__ out,
    int B)
{
    const int sub        = threadIdx.x & 15;           // float4 slot within row
    const int grp_local  = threadIdx.x >> 4;           // group within block (0..15)
    const int grps_per_b = blockDim.x >> 4;            // 16
    const int grp_stride = gridDim.x * grps_per_b;     // total concurrent groups
    const int ngroups    = B / RPG;                    // full groups of 4 rows

    const float4* __restrict__ U4 = reinterpret_cast<const float4*>(U);
    const float4* __restrict__ V4 = reinterpret_cast<const float4*>(V);
    const int4*   __restrict__ users4 = reinterpret_cast<const int4*>(users);
    const int4*   __restrict__ jokes4 = reinterpret_cast<const int4*>(jokes);

    const float g0 = g[0];

    int grp = blockIdx.x * grps_per_b + grp_local;

    // ---- scalar tail (rows beyond ngroups*RPG; empty for B = 1<<20) ----
    if (blockIdx.x == 0 && threadIdx.x == 0) {
        for (int row = ngroups * RPG; row < B; ++row) {
            const int ui = users[row], ji = jokes[row];
            float d = 0.f;
            for (int k = 0; k < 64; ++k) d += U[(size_t)ui * 64 + k] * V[(size_t)ji * 64 + k];
            out[row] = d + a[ui] + b[ji] + g0;
        }
    }

    if (grp >= ngroups) return;

    // ---- pipeline prologue: first iteration's indices ----
    int4 u4 = users4[grp];
    int4 j4 = jokes4[grp];

    while (grp < ngroups) {
        const int ui[RPG] = {u4.x, u4.y, u4.z, u4.w};
        const int ji[RPG] = {j4.x, j4.y, j4.z, j4.w};

        // Issue row gathers interleaved (u0,v0,u1,v1,...) so the first
        // reduction's vmcnt wait leaves the later pairs in flight.
        float4 uu[RPG], vv[RPG];
#pragma unroll
        for (int r = 0; r < RPG; ++r) {
            uu[r] = U4[(size_t)ui[r] * KV + sub];
            vv[r] = V4[(size_t)ji[r] * KV + sub];
        }

        // Bias loads issued NOW (overlap with row-gather misses), not at
        // the end. Uniform across the 16-lane group -> broadcast lines.
        float ab[RPG], bb[RPG];
#pragma unroll
        for (int r = 0; r < RPG; ++r) {
            ab[r] = a[ui[r]];
            bb[r] = b[ji[r]];
        }

        // Prefetch next iteration's indices while gathers are in flight.
        const int next = grp + grp_stride;
        if (next < ngroups) {
            u4 = users4[next];
            j4 = jokes4[next];
        }

        const int base = grp * RPG;
#pragma unroll
        for (int r = 0; r < RPG; ++r) {
            float d = uu[r].x * vv[r].x + uu[r].y * vv[r].y
                    + uu[r].z * vv[r].z + uu[r].w * vv[r].w;
            d += __shfl_down(d, 8, 16);
            d += __shfl_down(d, 4, 16);
            d += __shfl_down(d, 2, 16);
            d += __shfl_down(d, 1, 16);
            if (sub == 0)
                out[base + r] = d + ab[r] + bb[r] + g0;
        }

        grp = next;
    }
}

extern "C" void kernel_launch(void* const* d_in, const int* in_sizes, int n_in,
                              void* d_out, int out_size, void* d_ws, size_t ws_size,
                              hipStream_t stream)
{
    const int*   users = (const int*)d_in[0];
    const int*   jokes = (const int*)d_in[1];
    const float* U     = (const float*)d_in[2];
    const float* V     = (const float*)d_in[3];
    const float* a     = (const float*)d_in[4];
    const float* b     = (const float*)d_in[5];
    const float* g     = (const float*)d_in[6];
    float*       out   = (float*)d_out;

    const int B = in_sizes[0];   // 1048576 rows

    // Persistent-style: 8 blocks/CU resident on 256 CUs -> 2048 blocks,
    // 32768 groups, 8 pipelined iterations per group over 262144 groups.
    const int block = 256;
    int grid = 2048;
    const int ngroups = B / RPG;
    const int max_grid = (ngroups + (block / 16) - 1) / (block / 16);
    if (grid > max_grid) grid = max_grid > 0 ? max_grid : 1;

    latent_linear_kernel<<<grid, block, 0, stream>>>(users, jokes, U, V, a, b, g, out, B);
}